// Round 3
// baseline (416.700 us; speedup 1.0000x reference)
//
#include <hip/hip_runtime.h>
#include <math.h>

// StackedLSTM: B=2048, T=2048, D=H=6, 2 layers, softmax(h_last) -> [2048, 6] fp32.
//
// R5: force v_pk_fma_f32. R4 evidence: busy-cycles/step 283 (R3, scalar) ->
// 272 (R4, ext_vector float2) — the backend scalarized the float2 math
// (__builtin_elementwise_fma did not select VOP3P packed fp32). R5 wraps the
// dot-product ops in inline asm:
//   v_pk_fma_f32 / v_pk_mul_f32 / v_pk_add_f32 (gfx90a+ packed fp32,
//   full-rate on CDNA4; "v" constraint on 64-bit ext_vector = aligned pair).
// Also: gate-pair distribution via 2 quad_perm DPPs (gf=dpp[0,0,2,2](gB),
// go=dpp[1,1,3,3](gB)) replacing 1 dpp + 2 cndmask.
// Everything else (lane layout, DPP ring, permlane32_swap cross-layer,
// exp2-domain weight folding, 32-step full unroll, padded Xs) = R4, verified.

#define TSTEPS 2048
#define LOG2E 1.442695040889f

typedef __attribute__((ext_vector_type(2))) float f2;
typedef __attribute__((ext_vector_type(2))) int int2v;

__device__ __forceinline__ float fast_rcp(float v) { return __builtin_amdgcn_rcpf(v); }

template <int CTRL>
__device__ __forceinline__ float dpp_f(float v) {
    return __int_as_float(__builtin_amdgcn_mov_dpp(__float_as_int(v), CTRL, 0xF, 0xF, true));
}

// ---- forced packed-fp32 ops (VOP3P) ----
__device__ __forceinline__ f2 pk_fma(f2 a, f2 b, f2 c) {
    f2 d;
    asm("v_pk_fma_f32 %0, %1, %2, %3" : "=v"(d) : "v"(a), "v"(b), "v"(c));
    return d;
}
__device__ __forceinline__ f2 pk_mul(f2 a, f2 b) {
    f2 d;
    asm("v_pk_mul_f32 %0, %1, %2" : "=v"(d) : "v"(a), "v"(b));
    return d;
}
__device__ __forceinline__ f2 pk_add(f2 a, f2 b) {
    f2 d;
    asm("v_pk_add_f32 %0, %1, %2" : "=v"(d) : "v"(a), "v"(b));
    return d;
}

#if __has_builtin(__builtin_amdgcn_exp2f)
#define EXP2F(x) __builtin_amdgcn_exp2f(x)
#else
#define EXP2F(x) __expf((x) * 0.69314718056f)
#endif

// Broadcast lower-half (layer-0) lanes' value to upper-half lanes at lane-32
// offset (orientation verified R3/R4).
__device__ __forceinline__ float layer_swap_lo(float v, int swapaddr) {
#if __has_builtin(__builtin_amdgcn_permlane32_swap)
    (void)swapaddr;
    int2v r = __builtin_amdgcn_permlane32_swap(__float_as_int(v), __float_as_int(v),
                                               false, false);
    return __int_as_float(r[0]);
#else
    return __int_as_float(__builtin_amdgcn_ds_bpermute(swapaddr, __float_as_int(v)));
#endif
}

__global__ __launch_bounds__(64, 1)
void stacked_lstm_kernel(const float* __restrict__ x,
                         const float* __restrict__ Wih0, const float* __restrict__ Whh0,
                         const float* __restrict__ bih0, const float* __restrict__ bhh0,
                         const float* __restrict__ Wih1, const float* __restrict__ Whh1,
                         const float* __restrict__ bih1, const float* __restrict__ bhh1,
                         float* __restrict__ out)
{
    // 196-float stride: slot offset bank-shifted by 8 (R4: conflicts == 0).
    __shared__ __align__(16) float Xs[2][2][196];
    __shared__ float Hb[2][8];

    const int lane = threadIdx.x;
    const int l = lane >> 5;            // layer (bit 5: permlane32_swap crosses it)
    const int s = (lane >> 4) & 1;      // batch slot
    const int j = (lane >> 1) & 7;      // unit 0..7 (6,7 dummy)
    const int p = lane & 1;             // gate pair: 0 -> (i,f), 1 -> (g,o)
    const int jc = (j < 6) ? j : 5;
    const int w12 = lane & 15;
    const bool loader = (l == 0) && (w12 < 12);
    const long b = (long)blockIdx.x * 2 + s;
    const int swapaddr = (lane ^ 32) << 2;

    const float* Wih = l ? Wih1 : Wih0;
    const float* Whh = l ? Whh1 : Whh0;
    const float* bih = l ? bih1 : bih0;
    const float* bhh = l ? bhh1 : bhh0;

    const int rowA = p * 12 + jc;       // p=0: i-row ; p=1: g-row
    const int rowB = rowA + 6;          // p=0: f-row ; p=1: o-row
    const float scaleA = p ? (2.0f * LOG2E) : LOG2E;
    const float scaleB = LOG2E;

    // Pre-rotated weight PAIRS: pair r2 half h multiplies ring value (j-(2*r2+h))&7.
    f2 whA_p[4], wiA_p[4], whB_p[4], wiB_p[4];
#pragma unroll
    for (int r2 = 0; r2 < 4; ++r2) {
#pragma unroll
        for (int hf = 0; hf < 2; ++hf) {
            const int r = 2 * r2 + hf;
            const int idx = (j - r) & 7;
            const bool okw = idx < 6;
            const int ic = okw ? idx : 0;
            whA_p[r2][hf] = okw ? Whh[rowA * 6 + ic] * scaleA : 0.0f;
            wiA_p[r2][hf] = okw ? Wih[rowA * 6 + ic] * scaleA : 0.0f;
            whB_p[r2][hf] = okw ? Whh[rowB * 6 + ic] * scaleB : 0.0f;
            wiB_p[r2][hf] = okw ? Wih[rowB * 6 + ic] * scaleB : 0.0f;
        }
    }
    const f2 biasA = { (bih[rowA] + bhh[rowA]) * scaleA, 0.0f };
    const f2 biasB = { (bih[rowB] + bhh[rowB]) * scaleB, 0.0f };
    const float K2 = 2.0f * LOG2E;
    const float mA = p ? 2.0f : K2;     // p=0: K2*sigmoid(i) carries c-domain scale
    const float nA = p ? 1.0f : K2;

    // ---- x staging: 32 steps (768 B) per slot, 12 loader lanes per slot ----
    const float* xb = x + b * (TSTEPS * 6);
    float4 pre0, pre1, pre2, pre3;

    auto LOADBLK = [&](int blk) {
        if (loader) {
            const float4* xv = (const float4*)(xb + blk * 192);
            pre0 = xv[w12 +  0];
            pre1 = xv[w12 + 12];
            pre2 = xv[w12 + 24];
            pre3 = xv[w12 + 36];
        }
    };
    auto WRITEBLK = [&](int buf) {
        if (loader) {
            float4* dst = (float4*)&Xs[s][buf][0];
            dst[w12 +  0] = pre0;
            dst[w12 + 12] = pre1;
            dst[w12 + 24] = pre2;
            dst[w12 + 36] = pre3;
        }
    };

    float hv = 0.0f;   // own-layer h_j
    float c  = 0.0f;   // cell state, 2*LOG2E domain

    // One timestep. row is compile-time constant at every call site.
    auto STEP = [&](const float* xbase, int row) {
        float xcur = xbase[row * 6];                 // ds_read_b32 offset:row*24
        float h0bc = layer_swap_lo(hv, swapaddr);
        float inv  = l ? h0bc : xcur;

        float h1r = dpp_f<0x122>(hv);
        float h2r = dpp_f<0x124>(hv);
        float h3r = dpp_f<0x126>(hv);
        float h4r = dpp_f<0x128>(hv);
        float h5r = dpp_f<0x12A>(hv);
        float h6r = dpp_f<0x12C>(hv);
        float h7r = dpp_f<0x12E>(hv);
        float i1r = dpp_f<0x122>(inv);
        float i2r = dpp_f<0x124>(inv);
        float i3r = dpp_f<0x126>(inv);
        float i4r = dpp_f<0x128>(inv);
        float i5r = dpp_f<0x12A>(inv);
        float i6r = dpp_f<0x12C>(inv);
        float i7r = dpp_f<0x12E>(inv);

        f2 H01 = { hv,  h1r }, H23 = { h2r, h3r }, H45 = { h4r, h5r }, H67 = { h6r, h7r };
        f2 I01 = { inv, i1r }, I23 = { i2r, i3r }, I45 = { i4r, i5r }, I67 = { i6r, i7r };

        // Row A: h-chain (4 pk_fma, bias-seeded) + inv-chain (pk_mul + 3 pk_fma)
        f2 aH = pk_fma(H01, whA_p[0], biasA);
        aH = pk_fma(H23, whA_p[1], aH);
        aH = pk_fma(H45, whA_p[2], aH);
        aH = pk_fma(H67, whA_p[3], aH);
        f2 aX = pk_mul(I01, wiA_p[0]);
        aX = pk_fma(I23, wiA_p[1], aX);
        aX = pk_fma(I45, wiA_p[2], aX);
        aX = pk_fma(I67, wiA_p[3], aX);
        f2 SA2 = pk_add(aH, aX);
        float sA = SA2.x + SA2.y;

        // Row B
        f2 bH = pk_fma(H01, whB_p[0], biasB);
        bH = pk_fma(H23, whB_p[1], bH);
        bH = pk_fma(H45, whB_p[2], bH);
        bH = pk_fma(H67, whB_p[3], bH);
        f2 bX = pk_mul(I01, wiB_p[0]);
        bX = pk_fma(I23, wiB_p[1], bX);
        bX = pk_fma(I45, wiB_p[2], bX);
        bX = pk_fma(I67, wiB_p[3], bX);
        f2 SB2 = pk_add(bH, bX);
        float sB = SB2.x + SB2.y;

        // activations (exp2-domain scales pre-folded)
        float eA = EXP2F(sA);
        float gA = fmaf(mA, -fast_rcp(1.0f + eA), nA);  // p=0: K2*sig(i), p=1: tanh(g)
        float eB = EXP2F(sB);
        float gB = 1.0f - fast_rcp(1.0f + eB);          // sigmoid (f or o)

        // pair distribution:
        //   ig = i*g (product of both pair lanes' A values, symmetric)
        //   gf = even lane's gB (f), go = odd lane's gB (o), via quad_perm
        float xA = dpp_f<0xB1>(gA);
        float ig = gA * xA;                    // K2 * i * g
        float gf = dpp_f<0xA0>(gB);            // quad_perm [0,0,2,2] -> f on both
        float go = dpp_f<0xF5>(gB);            // quad_perm [1,1,3,3] -> o on both
        c = fmaf(gf, c, ig);
        float ec = EXP2F(c);                   // e^{2*c_true}
        float th = fmaf(2.0f, -fast_rcp(1.0f + ec), 1.0f);
        hv = go * th;
    };

    // ---- prologue ----
    LOADBLK(0);
    WRITEBLK(0);
    LOADBLK(1);
    __builtin_amdgcn_wave_barrier();

    const float* xb0 = &Xs[s][0][jc];
    const float* xb1 = &Xs[s][1][jc];

    // t=0 (layer-1's step is fictitious: zero its state once, off the loop)
    STEP(xb0, 0);
    if (l) { hv = 0.0f; c = 0.0f; }
#pragma unroll
    for (int row = 1; row < 32; ++row) STEP(xb0, row);   // t=1..31

    for (int k = 1; k < 64; ++k) {
        const int buf = k & 1;
        WRITEBLK(buf);
        if (k < 63) LOADBLK(k + 1);
        __builtin_amdgcn_wave_barrier();
        const float* xbase = buf ? xb1 : xb0;
#pragma unroll
        for (int row = 0; row < 32; ++row) STEP(xbase, row);  // t=32k..32k+31
    }
    STEP(xb1, 0);   // t=2048: layer-0 output unused; layer-1 consumes h0(2047)

    // ---- epilogue: hv on layer-1 lanes is h1(T-1); softmax ----
    if (l == 1 && p == 0 && j < 6) Hb[s][j] = hv;
    __builtin_amdgcn_wave_barrier();

    if (l == 0 && w12 < 6) {
        const float* hp = &Hb[s][0];
        float2 u0 = *(const float2*)(hp + 0);
        float2 u1 = *(const float2*)(hp + 2);
        float2 u2 = *(const float2*)(hp + 4);
        float v0 = u0.x, v1 = u0.y, v2 = u1.x, v3 = u1.y, v4 = u2.x, v5 = u2.y;
        float m = fmaxf(fmaxf(fmaxf(v0, v1), fmaxf(v2, v3)), fmaxf(v4, v5));
        float e0 = __expf(v0 - m), e1 = __expf(v1 - m), e2 = __expf(v2 - m);
        float e3 = __expf(v3 - m), e4 = __expf(v4 - m), e5 = __expf(v5 - m);
        float sum = ((e0 + e1) + (e2 + e3)) + (e4 + e5);
        float r = fast_rcp(sum);
        float mine = (w12 == 0) ? e0 : (w12 == 1) ? e1 : (w12 == 2) ? e2
                   : (w12 == 3) ? e3 : (w12 == 4) ? e4 : e5;
        out[b * 6 + w12] = mine * r;
    }
}

extern "C" void kernel_launch(void* const* d_in, const int* in_sizes, int n_in,
                              void* d_out, int out_size, void* d_ws, size_t ws_size,
                              hipStream_t stream) {
    (void)in_sizes; (void)n_in; (void)d_ws; (void)ws_size; (void)out_size;
    const float* x    = (const float*)d_in[0];
    const float* Wih0 = (const float*)d_in[1];
    const float* Whh0 = (const float*)d_in[2];
    const float* bih0 = (const float*)d_in[3];
    const float* bhh0 = (const float*)d_in[4];
    const float* Wih1 = (const float*)d_in[5];
    const float* Whh1 = (const float*)d_in[6];
    const float* bih1 = (const float*)d_in[7];
    const float* bhh1 = (const float*)d_in[8];
    float* outp = (float*)d_out;

    // 2048 batch / 2 per wave = 1024 blocks of 64 threads = 1 wave per SIMD.
    stacked_lstm_kernel<<<1024, 64, 0, stream>>>(
        x, Wih0, Whh0, bih0, bhh0, Wih1, Whh1, bih1, bhh1, outp);
}